// Round 3
// baseline (589.191 us; speedup 1.0000x reference)
//
#include <hip/hip_runtime.h>
#include <math.h>

// GCNGuard forward: 2 layers of {cosine-sim edge attention -> linear -> SPMM}.
// Strategy: build CSR once (edges sorted by row), then per layer:
//   att (SDDMM, 16 lanes/edge) -> rowsum/deg (thread/row) -> GEMM (LDS-tiled f32)
//   -> SPMM (wave/row, register accum, no atomics; fuses relu + next-layer norms).

constexpr int D_IN = 128;
constexpr int D_H  = 128;
constexpr int D_O  = 64;

typedef unsigned int uint;

// ---------------- node norms: one wave per node (D=128, 2 floats/lane) -------
__global__ __launch_bounds__(256) void node_norm_kernel(
    const float* __restrict__ x, float* __restrict__ nrm, int n) {
  int gid = blockIdx.x * blockDim.x + threadIdx.x;
  int i = gid >> 6;
  if (i >= n) return;
  int l = threadIdx.x & 63;
  float2 v = *reinterpret_cast<const float2*>(x + (size_t)i * 128 + l * 2);
  float s = v.x * v.x + v.y * v.y;
#pragma unroll
  for (int m = 1; m < 64; m <<= 1) s += __shfl_xor(s, m);
  if (l == 0) nrm[i] = sqrtf(s);
}

// ---------------- CSR build --------------------------------------------------
__global__ __launch_bounds__(256) void hist_kernel(
    const int* __restrict__ row, uint* __restrict__ counts, int nE) {
  int e = blockIdx.x * blockDim.x + threadIdx.x;
  if (e < nE) atomicAdd(&counts[row[e]], 1u);
}

// single-block scan: 1024 threads, serial chunk + Hillis-Steele over partials
__global__ __launch_bounds__(1024) void scan_kernel(
    const uint* __restrict__ counts, uint* __restrict__ row_ptr,
    uint* __restrict__ cursor, int n) {
  __shared__ uint ps[1024];
  int t = threadIdx.x;
  int chunk = (n + 1023) >> 10;
  int s = t * chunk;
  int e = min(s + chunk, n);
  uint sum = 0;
  for (int i = s; i < e; ++i) sum += counts[i];
  ps[t] = sum;
  __syncthreads();
  for (int off = 1; off < 1024; off <<= 1) {
    uint v = (t >= off) ? ps[t - off] : 0u;
    __syncthreads();
    ps[t] += v;
    __syncthreads();
  }
  uint run = ps[t] - sum;  // exclusive prefix
  for (int i = s; i < e; ++i) {
    row_ptr[i] = run;
    cursor[i] = run;
    run += counts[i];
  }
  if (t == 1023) row_ptr[n] = ps[1023];
}

__global__ __launch_bounds__(256) void scatter_kernel(
    const int* __restrict__ row, const int* __restrict__ col,
    uint* __restrict__ cursor, uint* __restrict__ row_s,
    uint* __restrict__ col_s, int nE) {
  int e = blockIdx.x * blockDim.x + threadIdx.x;
  if (e >= nE) return;
  int r = row[e];
  uint p = atomicAdd(&cursor[r], 1u);
  row_s[p] = (uint)r;
  col_s[p] = (uint)col[e];
}

// ---------------- W transpose (once per call, tiny) --------------------------
__global__ __launch_bounds__(256) void transpose_kernel(
    const float* __restrict__ W, float* __restrict__ Wt, int J, int K) {
  int idx = blockIdx.x * blockDim.x + threadIdx.x;
  if (idx >= J * K) return;
  int j = idx >> 7;        // K == 128 always here
  int k = idx & 127;
  Wt[k * J + j] = W[idx];
}

// ---------------- attention SDDMM: 16 lanes per edge, sorted order ----------
template <bool MASKED>
__global__ __launch_bounds__(256) void att_kernel(
    const float* __restrict__ x, const float* __restrict__ nrm,
    const uint* __restrict__ row_s, const uint* __restrict__ col_s,
    const float* __restrict__ mask_sim, float* __restrict__ sim_out, int nE) {
  int p = blockIdx.x * 16 + (threadIdx.x >> 4);
  if (p >= nE) return;
  int sl = threadIdx.x & 15;
  uint r = row_s[p], c = col_s[p];
  const float4* xr = reinterpret_cast<const float4*>(x + (size_t)r * 128);
  const float4* xc = reinterpret_cast<const float4*>(x + (size_t)c * 128);
  float4 a0 = xr[sl * 2], a1 = xr[sl * 2 + 1];
  float4 b0 = xc[sl * 2], b1 = xc[sl * 2 + 1];
  float d = a0.x * b0.x + a0.y * b0.y + a0.z * b0.z + a0.w * b0.w +
            a1.x * b1.x + a1.y * b1.y + a1.z * b1.z + a1.w * b1.w;
  d += __shfl_xor(d, 1);
  d += __shfl_xor(d, 2);
  d += __shfl_xor(d, 4);
  d += __shfl_xor(d, 8);
  if (sl == 0) {
    float sim = d / fmaxf(nrm[r] * nrm[c], 1e-12f);
    bool ok = (sim >= 0.1f);
    if (MASKED) ok = ok && (mask_sim[p] > 0.0f);
    sim_out[p] = ok ? sim : 0.0f;
  }
}

// ---------------- per-row sums + self-loop weight ---------------------------
__global__ __launch_bounds__(256) void rowdeg_kernel(
    const float* __restrict__ sim_s, const uint* __restrict__ row_ptr,
    float* __restrict__ rowsum, float* __restrict__ wself, int n) {
  int i = blockIdx.x * blockDim.x + threadIdx.x;
  if (i >= n) return;
  uint p0 = row_ptr[i], p1 = row_ptr[i + 1];
  float s = 0.f, d = 0.f;
  for (uint p = p0; p < p1; ++p) {
    float v = sim_s[p];
    s += v;
    if (v > 0.f) d += 1.f;
  }
  rowsum[i] = s;
  wself[i] = expf(1.0f / (d + 1.0f));
}

// ---------------- f32 GEMM: H[M][DOUT] = X[M][128] @ Wt[128][DOUT] + b ------
// 64x64 tile, 4x4 register blocking, conflict-free LDS read paths.
template <int DOUT>
__global__ __launch_bounds__(256) void gemm_kernel(
    const float* __restrict__ X, const float* __restrict__ Wt,
    const float* __restrict__ bias, float* __restrict__ H, int M) {
  __shared__ float xs[64][132];   // +4 pad: a-reads land 2-way (free)
  __shared__ float wl[128][64];   // [k][j], staged linearly -> conflict-free
  int i0 = blockIdx.x * 64;
  int j0 = blockIdx.y * 64;
  int t = threadIdx.x;
#pragma unroll
  for (int it = 0; it < 8; ++it) {           // stage W block: 2048 float4
    int idx = it * 256 + t;
    int k = idx >> 4, jq = idx & 15;
    float4 v = *reinterpret_cast<const float4*>(Wt + (size_t)k * DOUT + j0 + jq * 4);
    *reinterpret_cast<float4*>(&wl[k][jq * 4]) = v;
  }
#pragma unroll
  for (int it = 0; it < 8; ++it) {           // stage X tile: 64 rows x 128
    int i = it * 8 + (t >> 5);
    int kq = t & 31;
    int row = i0 + i;
    float4 v = make_float4(0.f, 0.f, 0.f, 0.f);
    if (row < M) v = *reinterpret_cast<const float4*>(X + (size_t)row * 128 + kq * 4);
    *reinterpret_cast<float4*>(&xs[i][kq * 4]) = v;
  }
  __syncthreads();
  int cg = t & 15, rg = t >> 4;
  int r0 = rg * 4, c0 = cg * 4;
  float acc[4][4] = {};
#pragma unroll 8
  for (int k = 0; k < 128; ++k) {
    float4 b4 = *reinterpret_cast<const float4*>(&wl[k][c0]);
    float a0 = xs[r0 + 0][k], a1 = xs[r0 + 1][k];
    float a2 = xs[r0 + 2][k], a3 = xs[r0 + 3][k];
    acc[0][0] += a0 * b4.x; acc[0][1] += a0 * b4.y; acc[0][2] += a0 * b4.z; acc[0][3] += a0 * b4.w;
    acc[1][0] += a1 * b4.x; acc[1][1] += a1 * b4.y; acc[1][2] += a1 * b4.z; acc[1][3] += a1 * b4.w;
    acc[2][0] += a2 * b4.x; acc[2][1] += a2 * b4.y; acc[2][2] += a2 * b4.z; acc[2][3] += a2 * b4.w;
    acc[3][0] += a3 * b4.x; acc[3][1] += a3 * b4.y; acc[3][2] += a3 * b4.z; acc[3][3] += a3 * b4.w;
  }
  float4 bb = *reinterpret_cast<const float4*>(bias + j0 + c0);
#pragma unroll
  for (int r = 0; r < 4; ++r) {
    int row = i0 + r0 + r;
    if (row < M) {
      float4 o = make_float4(acc[r][0] + bb.x, acc[r][1] + bb.y,
                             acc[r][2] + bb.z, acc[r][3] + bb.w);
      *reinterpret_cast<float4*>(H + (size_t)row * DOUT + j0 + c0) = o;
    }
  }
}

// ---------------- SPMM: wave per row, register accum, fused epilogue --------
template <int D, bool RELU, bool WRITE_NORM>
__global__ __launch_bounds__(256) void spmm_kernel(
    const float* __restrict__ H, const float* __restrict__ sim_s,
    const uint* __restrict__ col_s, const uint* __restrict__ row_ptr,
    const float* __restrict__ rowsum, const float* __restrict__ wself,
    float* __restrict__ out, float* __restrict__ norm_out, int n) {
  int gid = blockIdx.x * blockDim.x + threadIdx.x;
  int i = gid >> 6;
  if (i >= n) return;
  int l = threadIdx.x & 63;
  float ws = wself[i];
  float inv = 1.0f / fmaxf(rowsum[i], 1e-30f);
  uint p1 = row_ptr[i + 1];

  if constexpr (D == 128) {
    float2 hv = *reinterpret_cast<const float2*>(H + (size_t)i * 128 + l * 2);
    float ax = ws * hv.x, ay = ws * hv.y;
    for (uint p = row_ptr[i]; p < p1; ++p) {
      float s = sim_s[p];
      if (s > 0.0f) {                       // wave-uniform branch
        float w = expf(s * inv);
        uint c = col_s[p];
        float2 hc = *reinterpret_cast<const float2*>(H + (size_t)c * 128 + l * 2);
        ax += w * hc.x;
        ay += w * hc.y;
      }
    }
    if (RELU) { ax = fmaxf(ax, 0.f); ay = fmaxf(ay, 0.f); }
    float2 o; o.x = ax; o.y = ay;
    *reinterpret_cast<float2*>(out + (size_t)i * 128 + l * 2) = o;
    if (WRITE_NORM) {
      float s = ax * ax + ay * ay;
#pragma unroll
      for (int m = 1; m < 64; m <<= 1) s += __shfl_xor(s, m);
      if (l == 0) norm_out[i] = sqrtf(s);
    }
  } else {  // D == 64
    float a = ws * H[(size_t)i * 64 + l];
    for (uint p = row_ptr[i]; p < p1; ++p) {
      float s = sim_s[p];
      if (s > 0.0f) {
        float w = expf(s * inv);
        uint c = col_s[p];
        a += w * H[(size_t)c * 64 + l];
      }
    }
    if (RELU) a = fmaxf(a, 0.f);
    out[(size_t)i * 64 + l] = a;
    if (WRITE_NORM) {
      float s = a * a;
#pragma unroll
      for (int m = 1; m < 64; m <<= 1) s += __shfl_xor(s, m);
      if (l == 0) norm_out[i] = sqrtf(s);
    }
  }
}

// ---------------- launch -----------------------------------------------------
extern "C" void kernel_launch(void* const* d_in, const int* in_sizes, int n_in,
                              void* d_out, int out_size, void* d_ws, size_t ws_size,
                              hipStream_t stream) {
  const float* x  = (const float*)d_in[0];
  const float* W0 = (const float*)d_in[1];
  const float* b0 = (const float*)d_in[2];
  const float* W1 = (const float*)d_in[3];
  const float* b1 = (const float*)d_in[4];
  const int* erow = (const int*)d_in[5];
  const int* ecol = (const int*)d_in[6];
  float* out = (float*)d_out;

  int nN = in_sizes[0] / D_IN;  // 50000
  int nE = in_sizes[5];         // 800000

  char* w = (char*)d_ws;
  auto alloc = [&](size_t bytes) {
    char* p = w;
    w += (bytes + 255) & ~(size_t)255;
    return p;
  };
  uint* counts   = (uint*)alloc((size_t)nN * 4);
  uint* cursor   = (uint*)alloc((size_t)nN * 4);
  uint* row_ptr  = (uint*)alloc(((size_t)nN + 1) * 4);
  uint* row_s    = (uint*)alloc((size_t)nE * 4);
  uint* col_s    = (uint*)alloc((size_t)nE * 4);
  float* sim0    = (float*)alloc((size_t)nE * 4);   // layer-1 mask = sim0 > 0
  float* sim1    = (float*)alloc((size_t)nE * 4);
  float* nrm0    = (float*)alloc((size_t)nN * 4);
  float* nrm1    = (float*)alloc((size_t)nN * 4);
  float* rowsum0 = (float*)alloc((size_t)nN * 4);
  float* rowsum1 = (float*)alloc((size_t)nN * 4);
  float* wself0  = (float*)alloc((size_t)nN * 4);
  float* wself1  = (float*)alloc((size_t)nN * 4);
  float* Wt0     = (float*)alloc((size_t)D_IN * D_H * 4);
  float* Wt1     = (float*)alloc((size_t)D_H * D_O * 4);
  float* hbuf    = (float*)alloc((size_t)nN * D_H * 4);
  float* x1      = (float*)alloc((size_t)nN * D_H * 4);

  hipMemsetAsync(counts, 0, (size_t)nN * 4, stream);

  node_norm_kernel<<<(nN * 64 + 255) / 256, 256, 0, stream>>>(x, nrm0, nN);
  hist_kernel<<<(nE + 255) / 256, 256, 0, stream>>>(erow, counts, nE);
  scan_kernel<<<1, 1024, 0, stream>>>(counts, row_ptr, cursor, nN);
  scatter_kernel<<<(nE + 255) / 256, 256, 0, stream>>>(erow, ecol, cursor, row_s, col_s, nE);
  transpose_kernel<<<(D_H * D_IN + 255) / 256, 256, 0, stream>>>(W0, Wt0, D_H, D_IN);
  transpose_kernel<<<(D_O * D_H + 255) / 256, 256, 0, stream>>>(W1, Wt1, D_O, D_H);

  // layer 0
  att_kernel<false><<<(nE + 15) / 16, 256, 0, stream>>>(x, nrm0, row_s, col_s, nullptr, sim0, nE);
  rowdeg_kernel<<<(nN + 255) / 256, 256, 0, stream>>>(sim0, row_ptr, rowsum0, wself0, nN);
  gemm_kernel<D_H><<<dim3((nN + 63) / 64, D_H / 64), 256, 0, stream>>>(x, Wt0, b0, hbuf, nN);
  spmm_kernel<D_H, true, true><<<(nN * 64 + 255) / 256, 256, 0, stream>>>(
      hbuf, sim0, col_s, row_ptr, rowsum0, wself0, x1, nrm1, nN);

  // layer 1 (mask = active edges of layer 0)
  att_kernel<true><<<(nE + 15) / 16, 256, 0, stream>>>(x1, nrm1, row_s, col_s, sim0, sim1, nE);
  rowdeg_kernel<<<(nN + 255) / 256, 256, 0, stream>>>(sim1, row_ptr, rowsum1, wself1, nN);
  gemm_kernel<D_O><<<dim3((nN + 63) / 64, 1), 256, 0, stream>>>(x1, Wt1, b1, hbuf, nN);
  spmm_kernel<D_O, false, false><<<(nN * 64 + 255) / 256, 256, 0, stream>>>(
      hbuf, sim1, col_s, row_ptr, rowsum1, wself1, out, nullptr, nN);
}

// Round 4
// 481.955 us; speedup vs baseline: 1.2225x; 1.2225x over previous
//
#include <hip/hip_runtime.h>
#include <math.h>

// GCNGuard forward: 2 layers of {cosine-sim edge attention -> linear -> SPMM}.
// Strategy: build CSR once (edges sorted by row), then per layer:
//   att (SDDMM, 16 lanes/edge) -> rowsum/deg (thread/row) -> GEMM (LDS-tiled f32)
//   -> SPMM (wave/row, register accum, no atomics; fuses relu + next-layer norms).
// R3: single-block scan was 113us (latency-bound on 1 CU, 0.14% occupancy)
//     -> 3-phase multi-block scan (block scans + sums scan + offset add).

constexpr int D_IN = 128;
constexpr int D_H  = 128;
constexpr int D_O  = 64;

typedef unsigned int uint;

// ---------------- node norms: one wave per node (D=128, 2 floats/lane) -------
__global__ __launch_bounds__(256) void node_norm_kernel(
    const float* __restrict__ x, float* __restrict__ nrm, int n) {
  int gid = blockIdx.x * blockDim.x + threadIdx.x;
  int i = gid >> 6;
  if (i >= n) return;
  int l = threadIdx.x & 63;
  float2 v = *reinterpret_cast<const float2*>(x + (size_t)i * 128 + l * 2);
  float s = v.x * v.x + v.y * v.y;
#pragma unroll
  for (int m = 1; m < 64; m <<= 1) s += __shfl_xor(s, m);
  if (l == 0) nrm[i] = sqrtf(s);
}

// ---------------- CSR build --------------------------------------------------
__global__ __launch_bounds__(256) void hist_kernel(
    const int* __restrict__ row, uint* __restrict__ counts, int nE) {
  int e = blockIdx.x * blockDim.x + threadIdx.x;
  if (e < nE) atomicAdd(&counts[row[e]], 1u);
}

// phase 1: per-block exclusive scan of 256 counts, emit block sum
__global__ __launch_bounds__(256) void block_scan_kernel(
    const uint* __restrict__ counts, uint* __restrict__ row_excl,
    uint* __restrict__ blk_sums, int n) {
  __shared__ uint sh[256];
  int t = threadIdx.x;
  int i = blockIdx.x * 256 + t;
  uint v = (i < n) ? counts[i] : 0u;
  sh[t] = v;
  __syncthreads();
#pragma unroll
  for (int off = 1; off < 256; off <<= 1) {
    uint u = (t >= off) ? sh[t - off] : 0u;
    __syncthreads();
    sh[t] += u;
    __syncthreads();
  }
  if (i < n) row_excl[i] = sh[t] - v;         // exclusive-in-block
  if (t == 255) blk_sums[blockIdx.x] = sh[255];
}

// phase 2: scan the block sums (nb <= 256) in one small block
__global__ __launch_bounds__(256) void scan_sums_kernel(
    const uint* __restrict__ blk_sums, uint* __restrict__ blk_offs, int nb) {
  __shared__ uint sh[256];
  int t = threadIdx.x;
  uint v = (t < nb) ? blk_sums[t] : 0u;
  sh[t] = v;
  __syncthreads();
#pragma unroll
  for (int off = 1; off < 256; off <<= 1) {
    uint u = (t >= off) ? sh[t - off] : 0u;
    __syncthreads();
    sh[t] += u;
    __syncthreads();
  }
  if (t < nb) blk_offs[t] = sh[t] - v;        // exclusive block offset
}

// phase 3: add block offsets, materialize row_ptr + cursor, cap row_ptr[n]
__global__ __launch_bounds__(256) void add_offs_kernel(
    uint* __restrict__ row_ptr, uint* __restrict__ cursor,
    const uint* __restrict__ blk_offs, int n, uint nE) {
  int i = blockIdx.x * 256 + threadIdx.x;
  if (i < n) {
    uint v = row_ptr[i] + blk_offs[blockIdx.x];
    row_ptr[i] = v;
    cursor[i] = v;
  }
  if (i == n) row_ptr[n] = nE;                // grid over-covers by <256
}

__global__ __launch_bounds__(256) void scatter_kernel(
    const int* __restrict__ row, const int* __restrict__ col,
    uint* __restrict__ cursor, uint* __restrict__ row_s,
    uint* __restrict__ col_s, int nE) {
  int e = blockIdx.x * blockDim.x + threadIdx.x;
  if (e >= nE) return;
  int r = row[e];
  uint p = atomicAdd(&cursor[r], 1u);
  row_s[p] = (uint)r;
  col_s[p] = (uint)col[e];
}

// ---------------- W transpose (once per call, tiny) --------------------------
__global__ __launch_bounds__(256) void transpose_kernel(
    const float* __restrict__ W, float* __restrict__ Wt, int J, int K) {
  int idx = blockIdx.x * blockDim.x + threadIdx.x;
  if (idx >= J * K) return;
  int j = idx >> 7;        // K == 128 always here
  int k = idx & 127;
  Wt[k * J + j] = W[idx];
}

// ---------------- attention SDDMM: 16 lanes per edge, sorted order ----------
template <bool MASKED>
__global__ __launch_bounds__(256) void att_kernel(
    const float* __restrict__ x, const float* __restrict__ nrm,
    const uint* __restrict__ row_s, const uint* __restrict__ col_s,
    const float* __restrict__ mask_sim, float* __restrict__ sim_out, int nE) {
  int p = blockIdx.x * 16 + (threadIdx.x >> 4);
  if (p >= nE) return;
  int sl = threadIdx.x & 15;
  uint r = row_s[p], c = col_s[p];
  const float4* xr = reinterpret_cast<const float4*>(x + (size_t)r * 128);
  const float4* xc = reinterpret_cast<const float4*>(x + (size_t)c * 128);
  float4 a0 = xr[sl * 2], a1 = xr[sl * 2 + 1];
  float4 b0 = xc[sl * 2], b1 = xc[sl * 2 + 1];
  float d = a0.x * b0.x + a0.y * b0.y + a0.z * b0.z + a0.w * b0.w +
            a1.x * b1.x + a1.y * b1.y + a1.z * b1.z + a1.w * b1.w;
  d += __shfl_xor(d, 1);
  d += __shfl_xor(d, 2);
  d += __shfl_xor(d, 4);
  d += __shfl_xor(d, 8);
  if (sl == 0) {
    float sim = d / fmaxf(nrm[r] * nrm[c], 1e-12f);
    bool ok = (sim >= 0.1f);
    if (MASKED) ok = ok && (mask_sim[p] > 0.0f);
    sim_out[p] = ok ? sim : 0.0f;
  }
}

// ---------------- per-row sums + self-loop weight ---------------------------
__global__ __launch_bounds__(256) void rowdeg_kernel(
    const float* __restrict__ sim_s, const uint* __restrict__ row_ptr,
    float* __restrict__ rowsum, float* __restrict__ wself, int n) {
  int i = blockIdx.x * blockDim.x + threadIdx.x;
  if (i >= n) return;
  uint p0 = row_ptr[i], p1 = row_ptr[i + 1];
  float s = 0.f, d = 0.f;
  for (uint p = p0; p < p1; ++p) {
    float v = sim_s[p];
    s += v;
    if (v > 0.f) d += 1.f;
  }
  rowsum[i] = s;
  wself[i] = expf(1.0f / (d + 1.0f));
}

// ---------------- f32 GEMM: H[M][DOUT] = X[M][128] @ Wt[128][DOUT] + b ------
// 64x64 tile, 4x4 register blocking, conflict-free LDS read paths.
template <int DOUT>
__global__ __launch_bounds__(256) void gemm_kernel(
    const float* __restrict__ X, const float* __restrict__ Wt,
    const float* __restrict__ bias, float* __restrict__ H, int M) {
  __shared__ float xs[64][132];   // +4 pad: a-reads land 2-way (free)
  __shared__ float wl[128][64];   // [k][j], staged linearly -> conflict-free
  int i0 = blockIdx.x * 64;
  int j0 = blockIdx.y * 64;
  int t = threadIdx.x;
#pragma unroll
  for (int it = 0; it < 8; ++it) {           // stage W block: 2048 float4
    int idx = it * 256 + t;
    int k = idx >> 4, jq = idx & 15;
    float4 v = *reinterpret_cast<const float4*>(Wt + (size_t)k * DOUT + j0 + jq * 4);
    *reinterpret_cast<float4*>(&wl[k][jq * 4]) = v;
  }
#pragma unroll
  for (int it = 0; it < 8; ++it) {           // stage X tile: 64 rows x 128
    int i = it * 8 + (t >> 5);
    int kq = t & 31;
    int row = i0 + i;
    float4 v = make_float4(0.f, 0.f, 0.f, 0.f);
    if (row < M) v = *reinterpret_cast<const float4*>(X + (size_t)row * 128 + kq * 4);
    *reinterpret_cast<float4*>(&xs[i][kq * 4]) = v;
  }
  __syncthreads();
  int cg = t & 15, rg = t >> 4;
  int r0 = rg * 4, c0 = cg * 4;
  float acc[4][4] = {};
#pragma unroll 8
  for (int k = 0; k < 128; ++k) {
    float4 b4 = *reinterpret_cast<const float4*>(&wl[k][c0]);
    float a0 = xs[r0 + 0][k], a1 = xs[r0 + 1][k];
    float a2 = xs[r0 + 2][k], a3 = xs[r0 + 3][k];
    acc[0][0] += a0 * b4.x; acc[0][1] += a0 * b4.y; acc[0][2] += a0 * b4.z; acc[0][3] += a0 * b4.w;
    acc[1][0] += a1 * b4.x; acc[1][1] += a1 * b4.y; acc[1][2] += a1 * b4.z; acc[1][3] += a1 * b4.w;
    acc[2][0] += a2 * b4.x; acc[2][1] += a2 * b4.y; acc[2][2] += a2 * b4.z; acc[2][3] += a2 * b4.w;
    acc[3][0] += a3 * b4.x; acc[3][1] += a3 * b4.y; acc[3][2] += a3 * b4.z; acc[3][3] += a3 * b4.w;
  }
  float4 bb = *reinterpret_cast<const float4*>(bias + j0 + c0);
#pragma unroll
  for (int r = 0; r < 4; ++r) {
    int row = i0 + r0 + r;
    if (row < M) {
      float4 o = make_float4(acc[r][0] + bb.x, acc[r][1] + bb.y,
                             acc[r][2] + bb.z, acc[r][3] + bb.w);
      *reinterpret_cast<float4*>(H + (size_t)row * DOUT + j0 + c0) = o;
    }
  }
}

// ---------------- SPMM: wave per row, register accum, fused epilogue --------
template <int D, bool RELU, bool WRITE_NORM>
__global__ __launch_bounds__(256) void spmm_kernel(
    const float* __restrict__ H, const float* __restrict__ sim_s,
    const uint* __restrict__ col_s, const uint* __restrict__ row_ptr,
    const float* __restrict__ rowsum, const float* __restrict__ wself,
    float* __restrict__ out, float* __restrict__ norm_out, int n) {
  int gid = blockIdx.x * blockDim.x + threadIdx.x;
  int i = gid >> 6;
  if (i >= n) return;
  int l = threadIdx.x & 63;
  float ws = wself[i];
  float inv = 1.0f / fmaxf(rowsum[i], 1e-30f);
  uint p1 = row_ptr[i + 1];

  if constexpr (D == 128) {
    float2 hv = *reinterpret_cast<const float2*>(H + (size_t)i * 128 + l * 2);
    float ax = ws * hv.x, ay = ws * hv.y;
    for (uint p = row_ptr[i]; p < p1; ++p) {
      float s = sim_s[p];
      if (s > 0.0f) {                       // wave-uniform branch
        float w = expf(s * inv);
        uint c = col_s[p];
        float2 hc = *reinterpret_cast<const float2*>(H + (size_t)c * 128 + l * 2);
        ax += w * hc.x;
        ay += w * hc.y;
      }
    }
    if (RELU) { ax = fmaxf(ax, 0.f); ay = fmaxf(ay, 0.f); }
    float2 o; o.x = ax; o.y = ay;
    *reinterpret_cast<float2*>(out + (size_t)i * 128 + l * 2) = o;
    if (WRITE_NORM) {
      float s = ax * ax + ay * ay;
#pragma unroll
      for (int m = 1; m < 64; m <<= 1) s += __shfl_xor(s, m);
      if (l == 0) norm_out[i] = sqrtf(s);
    }
  } else {  // D == 64
    float a = ws * H[(size_t)i * 64 + l];
    for (uint p = row_ptr[i]; p < p1; ++p) {
      float s = sim_s[p];
      if (s > 0.0f) {
        float w = expf(s * inv);
        uint c = col_s[p];
        a += w * H[(size_t)c * 64 + l];
      }
    }
    if (RELU) a = fmaxf(a, 0.f);
    out[(size_t)i * 64 + l] = a;
    if (WRITE_NORM) {
      float s = a * a;
#pragma unroll
      for (int m = 1; m < 64; m <<= 1) s += __shfl_xor(s, m);
      if (l == 0) norm_out[i] = sqrtf(s);
    }
  }
}

// ---------------- launch -----------------------------------------------------
extern "C" void kernel_launch(void* const* d_in, const int* in_sizes, int n_in,
                              void* d_out, int out_size, void* d_ws, size_t ws_size,
                              hipStream_t stream) {
  const float* x  = (const float*)d_in[0];
  const float* W0 = (const float*)d_in[1];
  const float* b0 = (const float*)d_in[2];
  const float* W1 = (const float*)d_in[3];
  const float* b1 = (const float*)d_in[4];
  const int* erow = (const int*)d_in[5];
  const int* ecol = (const int*)d_in[6];
  float* out = (float*)d_out;

  int nN = in_sizes[0] / D_IN;  // 50000
  int nE = in_sizes[5];         // 800000
  int nBlk = (nN + 255) / 256;  // 196 scan blocks

  char* w = (char*)d_ws;
  auto alloc = [&](size_t bytes) {
    char* p = w;
    w += (bytes + 255) & ~(size_t)255;
    return p;
  };
  uint* counts   = (uint*)alloc((size_t)nN * 4);
  uint* cursor   = (uint*)alloc((size_t)nN * 4);
  uint* row_ptr  = (uint*)alloc(((size_t)nN + 1) * 4);
  uint* blk_sums = (uint*)alloc((size_t)nBlk * 4);
  uint* blk_offs = (uint*)alloc((size_t)nBlk * 4);
  uint* row_s    = (uint*)alloc((size_t)nE * 4);
  uint* col_s    = (uint*)alloc((size_t)nE * 4);
  float* sim0    = (float*)alloc((size_t)nE * 4);   // layer-1 mask = sim0 > 0
  float* sim1    = (float*)alloc((size_t)nE * 4);
  float* nrm0    = (float*)alloc((size_t)nN * 4);
  float* nrm1    = (float*)alloc((size_t)nN * 4);
  float* rowsum0 = (float*)alloc((size_t)nN * 4);
  float* rowsum1 = (float*)alloc((size_t)nN * 4);
  float* wself0  = (float*)alloc((size_t)nN * 4);
  float* wself1  = (float*)alloc((size_t)nN * 4);
  float* Wt0     = (float*)alloc((size_t)D_IN * D_H * 4);
  float* Wt1     = (float*)alloc((size_t)D_H * D_O * 4);
  float* hbuf    = (float*)alloc((size_t)nN * D_H * 4);
  float* x1      = (float*)alloc((size_t)nN * D_H * 4);

  hipMemsetAsync(counts, 0, (size_t)nN * 4, stream);

  node_norm_kernel<<<(nN * 64 + 255) / 256, 256, 0, stream>>>(x, nrm0, nN);
  hist_kernel<<<(nE + 255) / 256, 256, 0, stream>>>(erow, counts, nE);
  block_scan_kernel<<<nBlk, 256, 0, stream>>>(counts, row_ptr, blk_sums, nN);
  scan_sums_kernel<<<1, 256, 0, stream>>>(blk_sums, blk_offs, nBlk);
  add_offs_kernel<<<nBlk, 256, 0, stream>>>(row_ptr, cursor, blk_offs, nN, (uint)nE);
  scatter_kernel<<<(nE + 255) / 256, 256, 0, stream>>>(erow, ecol, cursor, row_s, col_s, nE);
  transpose_kernel<<<(D_H * D_IN + 255) / 256, 256, 0, stream>>>(W0, Wt0, D_H, D_IN);
  transpose_kernel<<<(D_O * D_H + 255) / 256, 256, 0, stream>>>(W1, Wt1, D_O, D_H);

  // layer 0
  att_kernel<false><<<(nE + 15) / 16, 256, 0, stream>>>(x, nrm0, row_s, col_s, nullptr, sim0, nE);
  rowdeg_kernel<<<(nN + 255) / 256, 256, 0, stream>>>(sim0, row_ptr, rowsum0, wself0, nN);
  gemm_kernel<D_H><<<dim3((nN + 63) / 64, D_H / 64), 256, 0, stream>>>(x, Wt0, b0, hbuf, nN);
  spmm_kernel<D_H, true, true><<<(nN * 64 + 255) / 256, 256, 0, stream>>>(
      hbuf, sim0, col_s, row_ptr, rowsum0, wself0, x1, nrm1, nN);

  // layer 1 (mask = active edges of layer 0)
  att_kernel<true><<<(nE + 15) / 16, 256, 0, stream>>>(x1, nrm1, row_s, col_s, sim0, sim1, nE);
  rowdeg_kernel<<<(nN + 255) / 256, 256, 0, stream>>>(sim1, row_ptr, rowsum1, wself1, nN);
  gemm_kernel<D_O><<<dim3((nN + 63) / 64, 1), 256, 0, stream>>>(x1, Wt1, b1, hbuf, nN);
  spmm_kernel<D_O, false, false><<<(nN * 64 + 255) / 256, 256, 0, stream>>>(
      hbuf, sim1, col_s, row_ptr, rowsum1, wself1, out, nullptr, nN);
}